// Round 14
// baseline (261.631 us; speedup 1.0000x reference)
//
#include <hip/hip_runtime.h>
#include <math.h>

#define N_NODES   500000
#define N_EDGES   16000000
#define EPS       1e-6f

#define NBINS         256      // bin = dst >> 11  (2048 nodes per bin)
#define NODES_PER_BIN 2048
#define CHUNK         4096     // edges per scatter block
#define NBLK_A        3907     // ceil(16e6 / 4096)
#define SPLIT         8        // reduce splits per bin
#define BPB           489      // ceil(NBLK_A / SPLIT)

#define PI_F     3.14159265358979f
#define HALFPI_F 1.57079632679490f
#define TWOPI    6.28318530717959f

typedef unsigned long long u64;
typedef unsigned int u32;
typedef unsigned short u16;
typedef u32 v4u __attribute__((ext_vector_type(4)));

// u32 record layout (proven, absmax 0.03125):
//   [ 0:11) lid  = dst & 2047
//   [11:23) tq   = round((atan2(dy,dx)+pi) * 4096/2pi) & 4095
//   [23:32) rq   = min(round(|d| * 32), 510);  rq==511 => zero-diff sentinel

__device__ inline float fast_atan2(float dy, float dx) {
    float ax = fabsf(dx), ay = fabsf(dy);
    float mx = fmaxf(ax, ay), mn = fminf(ax, ay);
    float a  = mn * __builtin_amdgcn_rcpf(mx);
    float t2 = a * a;
    float p  = fmaf(fmaf(fmaf(fmaf(0.0208351f, t2, -0.0851330f),
                              t2, 0.1801410f), t2, -0.3302995f), t2, 0.9998660f);
    float th = a * p;
    if (ay > ax) th = HALFPI_F - th;
    if (dx < 0.0f) th = PI_F - th;
    return copysignf(th, dy);
}

// decode one record -> packed u64 accumulator delta
__device__ inline u64 decode_rec(u32 rc) {
    u32 tq = (rc >> 11) & 4095u;
    u32 rq = rc >> 23;
    if (rq == 511u) {
        return (u64)192 | ((u64)192 << 16) | ((u64)16 << 32)
             | ((u64)16 << 44) | (1ULL << 56);
    }
    float th = (float)tq * (TWOPI / 4096.0f) - PI_F;
    float sn, cs;
    __sincosf(th, &sn, &cs);
    float r = (float)rq * (1.0f / 32.0f);
    float dxr = fminf(fmaxf(r * cs, -12.0f), 12.0f);
    float dyr = fminf(fmaxf(r * sn, -12.0f), 12.0f);
    u32 qdx = (u32)__float2int_rn((dxr + 12.0f) * 16.0f);
    u32 qdy = (u32)__float2int_rn((dyr + 12.0f) * 16.0f);
    u32 qux = (u32)__float2int_rn((cs + 1.0f) * 16.0f);
    u32 quy = (u32)__float2int_rn((sn + 1.0f) * 16.0f);
    return (u64)qdx | ((u64)qdy << 16) | ((u64)qux << 32)
         | ((u64)quy << 44) | (1ULL << 56);
}

// ---- Kernel 1: build records, block-local counting sort, streaming writeout ----
// CHUNK=4096 -> ~25 KB LDS -> 4 blocks/CU (32 waves, occupancy cap) to hide
// the random pos-gather latency.
__global__ void __launch_bounds__(512) scatter_kernel(
    const int* __restrict__ src, const int* __restrict__ dst,
    const float* __restrict__ pos,
    u32* __restrict__ recbuf, u32* __restrict__ inclbuf)
{
    __shared__ u32 stage[CHUNK];       // 16 KB
    __shared__ u16 perm[CHUNK];        // 8 KB
    __shared__ u32 incl[NBINS];        // 1 KB
    __shared__ u32 wsum[4];

    int t = threadIdx.x, b = blockIdx.x;
    int lane = t & 63, wid = t >> 6;
    if (t < NBINS) incl[t] = 0;
    __syncthreads();

    const v4u* src4 = reinterpret_cast<const v4u*>(src);
    const v4u* dst4 = reinterpret_cast<const v4u*>(dst);
    int base4 = b * (CHUNK / 4);

    u32 rb[8];                         // bin(8) << 13 | rank(13); ~0u = invalid
    #pragma unroll
    for (int i = 0; i < 2; ++i) {
        int e4 = base4 + t + i * 512;
        #pragma unroll
        for (int j = 0; j < 4; ++j) rb[i * 4 + j] = 0xFFFFFFFFu;
        if (e4 * 4 < N_EDGES) {
            v4u s4 = __builtin_nontemporal_load(src4 + e4);
            v4u d4 = __builtin_nontemporal_load(dst4 + e4);
            #pragma unroll
            for (int j = 0; j < 4; ++j) {
                int s_ = min(max((int)s4[j], 0), N_NODES - 1);
                int d_ = min(max((int)d4[j], 0), N_NODES - 1);
                float2 ps = reinterpret_cast<const float2*>(pos)[s_];
                float2 pd = reinterpret_cast<const float2*>(pos)[d_];
                float dx = ps.x - pd.x;
                float dy = ps.y - pd.y;
                float r2 = dx * dx + dy * dy;
                u32 lid = (u32)d_ & (NODES_PER_BIN - 1);
                u32 rc;
                if (r2 == 0.0f) {
                    rc = lid | (511u << 23);
                } else {
                    float nrm = sqrtf(r2);
                    float th = fast_atan2(dy, dx);
                    u32 tq = ((u32)__float2int_rn((th + PI_F) * (4096.0f / TWOPI))) & 4095u;
                    u32 rq = (u32)min(__float2int_rn(nrm * 32.0f), 510);
                    rc = lid | (tq << 11) | (rq << 23);
                }
                int k = i * 4 + j;
                stage[t + k * 512] = rc;
                u32 bin = ((u32)d_) >> 11;
                u32 r = atomicAdd(&incl[bin], 1u);
                rb[k] = (bin << 13) | r;
            }
        }
    }
    __syncthreads();

    u32 v = 0;
    if (t < NBINS) {
        v = incl[t];
        #pragma unroll
        for (int off = 1; off < 64; off <<= 1) {
            u32 u_ = __shfl_up(v, off, 64);
            if (lane >= off) v += u_;
        }
        if (lane == 63) wsum[wid] = v;
    }
    __syncthreads();
    if (t < NBINS) {
        u32 pre = 0;
        #pragma unroll
        for (int w2 = 0; w2 < 4; ++w2)
            pre += (w2 < wid) ? wsum[w2] : 0;
        v += pre;
        incl[t] = v;
        __builtin_nontemporal_store(v, inclbuf + (size_t)b * NBINS + t);
    }
    __syncthreads();

    #pragma unroll
    for (int k = 0; k < 8; ++k) {
        if (rb[k] != 0xFFFFFFFFu) {
            u32 bin = rb[k] >> 13;
            u32 r   = rb[k] & 8191u;
            u32 excl = bin ? incl[bin - 1] : 0;
            perm[excl + r] = (u16)(t + k * 512);
        }
    }
    __syncthreads();

    v4u* out4 = reinterpret_cast<v4u*>(recbuf + (size_t)b * CHUNK);
    #pragma unroll
    for (int i = 0; i < 2; ++i) {
        int j4 = t + i * 512;
        v4u o;
        o[0] = stage[perm[j4 * 4 + 0] & (CHUNK - 1)];
        o[1] = stage[perm[j4 * 4 + 1] & (CHUNK - 1)];
        o[2] = stage[perm[j4 * 4 + 2] & (CHUNK - 1)];
        o[3] = stage[perm[j4 * 4 + 3] & (CHUNK - 1)];
        __builtin_nontemporal_store(o, out4 + j4);
    }
}

// ---- Kernel 2: split-K run gather + LDS accumulate -> partial streams ----
__global__ void __launch_bounds__(512) reduce_kernel(
    const u32* __restrict__ recbuf, const u32* __restrict__ inclbuf,
    u64* __restrict__ partial)
{
    __shared__ u64 acc[NODES_PER_BIN];   // 16 KB
    int t = threadIdx.x;
    int k = blockIdx.x / SPLIT;
    int s = blockIdx.x % SPLIT;
    int lane = t & 63, wid = t >> 6;
    #pragma unroll
    for (int i = 0; i < 4; ++i) acc[t + i * 512] = 0;
    __syncthreads();

    int b0 = s * BPB;
    int b1 = min(b0 + BPB, NBLK_A);
    int half = lane >> 5;
    int sub  = lane & 31;
    for (int bb = b0 + wid * 2; bb < b1; bb += 16) {
        int b = bb + half;
        u32 lo = 0, hi = 0;
        if (b < b1) {
            const u32* ib = inclbuf + (size_t)b * NBINS;
            hi = ib[k];
            lo = k ? ib[k - 1] : 0;
        }
        const u32* seg = recbuf + (size_t)b * CHUNK;
        for (u32 j = lo + sub; j < hi; j += 32) {
            u32 rc = __builtin_nontemporal_load(seg + j);
            atomicAdd(&acc[rc & (NODES_PER_BIN - 1)], decode_rec(rc));
        }
    }
    __syncthreads();

    u64* dstp = partial + ((size_t)k * SPLIT + s) * NODES_PER_BIN;
    #pragma unroll
    for (int i = 0; i < 4; ++i) {
        int idx = t + i * 512;
        __builtin_nontemporal_store(acc[idx], dstp + idx);
    }
}

// ---- Kernel 3: combine partials + finalize ----
__global__ void __launch_bounds__(512) combine_kernel(
    const u64* __restrict__ partial, const float* __restrict__ pos,
    float* __restrict__ out)
{
    int i = blockIdx.x * 512 + threadIdx.x;
    if (i >= N_NODES) return;
    int k = i >> 11;
    int lid = i & (NODES_PER_BIN - 1);
    const u64* p = partial + (size_t)k * SPLIT * NODES_PER_BIN + lid;
    u64 w = 0;
    #pragma unroll
    for (int s = 0; s < SPLIT; ++s)
        w += __builtin_nontemporal_load(p + (size_t)s * NODES_PER_BIN);

    float cnt = (float)(u32)(w >> 56);
    float sdx = (float)(u32)(w & 0xFFFFULL)         * (1.0f/16.0f) - 12.0f * cnt;
    float sdy = (float)(u32)((w >> 16) & 0xFFFFULL) * (1.0f/16.0f) - 12.0f * cnt;
    float sux = (float)(u32)((w >> 32) & 0xFFFULL)  * (1.0f/16.0f) -  1.0f * cnt;
    float suy = (float)(u32)((w >> 44) & 0xFFFULL)  * (1.0f/16.0f) -  1.0f * cnt;
    float invc = 1.0f / fmaxf(cnt, 1.0f);
    float2 pp = reinterpret_cast<const float2*>(pos)[i];
    float* row = out + (size_t)i * 6;
    row[0] = sdx * invc;
    row[1] = sdy * invc;
    row[2] = sux * invc;
    row[3] = suy * invc;
    row[4] = pp.x;
    row[5] = pp.y;
}

// ---------------- Fallback (round-3 single-atomic path) ----------------
__global__ void __launch_bounds__(256) edge_scatter_kernel(
    const int* __restrict__ src, const int* __restrict__ dst,
    const float* __restrict__ pos, u64* __restrict__ acc)
{
    int e = blockIdx.x * blockDim.x + threadIdx.x;
    if (e >= N_EDGES) return;
    int s = src[e];
    int d = dst[e];
    if ((unsigned)s >= (unsigned)N_NODES || (unsigned)d >= (unsigned)N_NODES) return;
    float2 ps = reinterpret_cast<const float2*>(pos)[s];
    float2 pd = reinterpret_cast<const float2*>(pos)[d];
    float dx = ps.x - pd.x, dy = ps.y - pd.y;
    float nrm = sqrtf(dx*dx + dy*dy) + EPS;
    float inv = 1.0f / nrm;
    float ux = dx * inv, uy = dy * inv;
    float cdx = fminf(fmaxf(dx, -12.0f), 12.0f);
    float cdy = fminf(fmaxf(dy, -12.0f), 12.0f);
    u64 qdx = (u64)(u32)__float2int_rn((cdx + 12.0f) * 16.0f);
    u64 qdy = (u64)(u32)__float2int_rn((cdy + 12.0f) * 16.0f);
    u64 qux = (u64)(u32)__float2int_rn((ux + 1.0f) * 16.0f);
    u64 quy = (u64)(u32)__float2int_rn((uy + 1.0f) * 16.0f);
    u64 w = qdx | (qdy << 16) | (qux << 32) | (quy << 44) | (1ULL << 56);
    atomicAdd(acc + (size_t)d * 3, w);
}

__global__ void __launch_bounds__(256) node_finalize_kernel(
    const float* __restrict__ pos, float* __restrict__ out)
{
    int i = blockIdx.x * blockDim.x + threadIdx.x;
    if (i >= N_NODES) return;
    u64 w = reinterpret_cast<const u64*>(out)[(size_t)i * 3];
    float cnt = (float)(u32)(w >> 56);
    float sdx = (float)(u32)(w & 0xFFFFULL)         * (1.0f/16.0f) - 12.0f * cnt;
    float sdy = (float)(u32)((w >> 16) & 0xFFFFULL) * (1.0f/16.0f) - 12.0f * cnt;
    float sux = (float)(u32)((w >> 32) & 0xFFFULL)  * (1.0f/16.0f) -  1.0f * cnt;
    float suy = (float)(u32)((w >> 44) & 0xFFFULL)  * (1.0f/16.0f) -  1.0f * cnt;
    float invc = 1.0f / fmaxf(cnt, 1.0f);
    float2 p = reinterpret_cast<const float2*>(pos)[i];
    float* row = out + (size_t)i * 6;
    row[0] = sdx * invc; row[1] = sdy * invc;
    row[2] = sux * invc; row[3] = suy * invc;
    row[4] = p.x; row[5] = p.y;
}

extern "C" void kernel_launch(void* const* d_in, const int* in_sizes, int n_in,
                              void* d_out, int out_size, void* d_ws, size_t ws_size,
                              hipStream_t stream)
{
    const float* pos = (const float*)d_in[0];
    const int* edge_index = (const int*)d_in[1];
    const int* src = edge_index;
    const int* dst = edge_index + N_EDGES;
    float* out = (float*)d_out;

    size_t need_rec  = (size_t)NBLK_A * CHUNK * sizeof(u32);                // ~64 MB
    size_t need_incl = (size_t)NBLK_A * NBINS * sizeof(u32);                // ~4 MB
    size_t need_part = (size_t)NBINS * SPLIT * NODES_PER_BIN * sizeof(u64); // 32 MB
    size_t need = need_rec + need_incl + need_part + 256;

    if (ws_size < need) {
        // Fallback: single-u64-atomic path (round 3)
        (void)hipMemsetAsync(d_out, 0, (size_t)out_size * sizeof(float), stream);
        int eblocks = (N_EDGES + 255) / 256;
        edge_scatter_kernel<<<eblocks, 256, 0, stream>>>(
            src, dst, pos, reinterpret_cast<u64*>(out));
        int nblocks = (N_NODES + 255) / 256;
        node_finalize_kernel<<<nblocks, 256, 0, stream>>>(pos, out);
        return;
    }

    char* w = (char*)d_ws;
    u32* recbuf  = (u32*)w;           w += need_rec;
    u32* inclbuf = (u32*)w;           w += need_incl;
    u64* partial = (u64*)w;

    scatter_kernel<<<NBLK_A, 512, 0, stream>>>(src, dst, pos, recbuf, inclbuf);
    reduce_kernel <<<NBINS * SPLIT, 512, 0, stream>>>(recbuf, inclbuf, partial);
    combine_kernel<<<(N_NODES + 511) / 512, 512, 0, stream>>>(partial, pos, out);
}

// Round 15
// 242.982 us; speedup vs baseline: 1.0768x; 1.0768x over previous
//
#include <hip/hip_runtime.h>
#include <math.h>

#define N_NODES   500000
#define N_EDGES   16000000
#define EPS       1e-6f

#define NBINS         256      // bin = dst >> 11  (2048 nodes per bin)
#define NODES_PER_BIN 2048
#define CHUNK         4096     // edges per scatter block
#define NBLK_A        3907     // ceil(16e6 / 4096)
#define SPLIT         8        // reduce splits per bin
#define BPB           489      // ceil(NBLK_A / SPLIT)

typedef unsigned long long u64;
typedef unsigned int u32;
typedef unsigned short u16;
typedef u32 v4u __attribute__((ext_vector_type(4)));

// u32 record layout: [0:11) lid = dst & 2047, [11:30) srcid (< 2^19), [30:32) spare.
// Geometry is computed at reduce time in exact f32 (round-3 proven math):
// pos[src] = random gather (only one left), pos[dst] = L1-hot 16 KB bin window.

// ---- Kernel 1: pure integer counting sort of edges by dst-bin ----
__global__ void __launch_bounds__(512) scatter_kernel(
    const int* __restrict__ src, const int* __restrict__ dst,
    u32* __restrict__ recbuf, u32* __restrict__ inclbuf)
{
    __shared__ u32 stage[CHUNK];       // 16 KB
    __shared__ u16 perm[CHUNK];        // 8 KB
    __shared__ u32 incl[NBINS];        // 1 KB
    __shared__ u32 wsum[4];

    int t = threadIdx.x, b = blockIdx.x;
    int lane = t & 63, wid = t >> 6;
    if (t < NBINS) incl[t] = 0;
    __syncthreads();

    const v4u* src4 = reinterpret_cast<const v4u*>(src);
    const v4u* dst4 = reinterpret_cast<const v4u*>(dst);
    int base4 = b * (CHUNK / 4);

    u32 rb[8];                         // bin(8) << 13 | rank(13); ~0u = invalid
    #pragma unroll
    for (int i = 0; i < 2; ++i) {
        int e4 = base4 + t + i * 512;
        #pragma unroll
        for (int j = 0; j < 4; ++j) rb[i * 4 + j] = 0xFFFFFFFFu;
        if (e4 * 4 < N_EDGES) {
            v4u s4 = __builtin_nontemporal_load(src4 + e4);
            v4u d4 = __builtin_nontemporal_load(dst4 + e4);
            #pragma unroll
            for (int j = 0; j < 4; ++j) {
                u32 s_ = (u32)min(max((int)s4[j], 0), N_NODES - 1);
                u32 d_ = (u32)min(max((int)d4[j], 0), N_NODES - 1);
                u32 rc = (s_ << 11) | (d_ & (NODES_PER_BIN - 1));
                int k = i * 4 + j;
                stage[t + k * 512] = rc;
                u32 bin = d_ >> 11;
                u32 r = atomicAdd(&incl[bin], 1u);
                rb[k] = (bin << 13) | r;
            }
        }
    }
    __syncthreads();

    // in-place inclusive scan of incl[256]
    u32 v = 0;
    if (t < NBINS) {
        v = incl[t];
        #pragma unroll
        for (int off = 1; off < 64; off <<= 1) {
            u32 u_ = __shfl_up(v, off, 64);
            if (lane >= off) v += u_;
        }
        if (lane == 63) wsum[wid] = v;
    }
    __syncthreads();
    if (t < NBINS) {
        u32 pre = 0;
        #pragma unroll
        for (int w2 = 0; w2 < 4; ++w2)
            pre += (w2 < wid) ? wsum[w2] : 0;
        v += pre;
        incl[t] = v;
        __builtin_nontemporal_store(v, inclbuf + (size_t)b * NBINS + t);
    }
    __syncthreads();

    #pragma unroll
    for (int k = 0; k < 8; ++k) {
        if (rb[k] != 0xFFFFFFFFu) {
            u32 bin = rb[k] >> 13;
            u32 r   = rb[k] & 8191u;
            u32 excl = bin ? incl[bin - 1] : 0;
            perm[excl + r] = (u16)(t + k * 512);
        }
    }
    __syncthreads();

    v4u* out4 = reinterpret_cast<v4u*>(recbuf + (size_t)b * CHUNK);
    #pragma unroll
    for (int i = 0; i < 2; ++i) {
        int j4 = t + i * 512;
        v4u o;
        o[0] = stage[perm[j4 * 4 + 0] & (CHUNK - 1)];
        o[1] = stage[perm[j4 * 4 + 1] & (CHUNK - 1)];
        o[2] = stage[perm[j4 * 4 + 2] & (CHUNK - 1)];
        o[3] = stage[perm[j4 * 4 + 3] & (CHUNK - 1)];
        __builtin_nontemporal_store(o, out4 + j4);
    }
}

// ---- Kernel 2: split-K decode + accumulate. 16-lane groups per run. ----
// Exact f32 geometry (matches reference incl. +EPS), packed-u64 acc at 1/16 grid.
__global__ void __launch_bounds__(512) reduce_kernel(
    const u32* __restrict__ recbuf, const u32* __restrict__ inclbuf,
    const float* __restrict__ pos, u64* __restrict__ partial)
{
    __shared__ u64 acc[NODES_PER_BIN];   // 16 KB
    int t = threadIdx.x;
    int k = blockIdx.x / SPLIT;
    int s = blockIdx.x % SPLIT;
    int lane = t & 63, wid = t >> 6;
    #pragma unroll
    for (int i = 0; i < 4; ++i) acc[t + i * 512] = 0;
    __syncthreads();

    const float2* pos2 = reinterpret_cast<const float2*>(pos);
    int nodebase = k * NODES_PER_BIN;
    int b0 = s * BPB;
    int b1 = min(b0 + BPB, NBLK_A);
    int g   = lane >> 4;                 // 4 groups of 16 lanes per wave
    int sub = lane & 15;
    for (int bb = b0 + wid * 4; bb < b1; bb += 32) {
        int b = bb + g;
        u32 lo = 0, hi = 0;
        if (b < b1) {
            const u32* ib = inclbuf + (size_t)b * NBINS;
            hi = ib[k];
            lo = k ? ib[k - 1] : 0;
        }
        const u32* seg = recbuf + (size_t)b * CHUNK;
        for (u32 j = lo + sub; j < hi; j += 16) {
            u32 rc = __builtin_nontemporal_load(seg + j);
            u32 lid  = rc & (NODES_PER_BIN - 1);
            u32 sidx = rc >> 11;
            float2 ps = pos2[sidx];              // the one random gather
            float2 pd = pos2[nodebase + lid];    // L1-hot 16 KB window
            float dx = ps.x - pd.x;
            float dy = ps.y - pd.y;
            float nrm = sqrtf(dx * dx + dy * dy) + EPS;
            float inv = 1.0f / nrm;
            float ux = dx * inv, uy = dy * inv;
            float cdx = fminf(fmaxf(dx, -12.0f), 12.0f);
            float cdy = fminf(fmaxf(dy, -12.0f), 12.0f);
            u32 qdx = (u32)__float2int_rn((cdx + 12.0f) * 16.0f);
            u32 qdy = (u32)__float2int_rn((cdy + 12.0f) * 16.0f);
            u32 qux = (u32)__float2int_rn((ux + 1.0f) * 16.0f);
            u32 quy = (u32)__float2int_rn((uy + 1.0f) * 16.0f);
            u64 w = (u64)qdx | ((u64)qdy << 16) | ((u64)qux << 32)
                  | ((u64)quy << 44) | (1ULL << 56);
            atomicAdd(&acc[lid], w);
        }
    }
    __syncthreads();

    u64* dstp = partial + ((size_t)k * SPLIT + s) * NODES_PER_BIN;
    #pragma unroll
    for (int i = 0; i < 4; ++i) {
        int idx = t + i * 512;
        __builtin_nontemporal_store(acc[idx], dstp + idx);
    }
}

// ---- Kernel 3: combine partials + finalize ----
__global__ void __launch_bounds__(512) combine_kernel(
    const u64* __restrict__ partial, const float* __restrict__ pos,
    float* __restrict__ out)
{
    int i = blockIdx.x * 512 + threadIdx.x;
    if (i >= N_NODES) return;
    int k = i >> 11;
    int lid = i & (NODES_PER_BIN - 1);
    const u64* p = partial + (size_t)k * SPLIT * NODES_PER_BIN + lid;
    u64 w = 0;
    #pragma unroll
    for (int s = 0; s < SPLIT; ++s)
        w += __builtin_nontemporal_load(p + (size_t)s * NODES_PER_BIN);

    float cnt = (float)(u32)(w >> 56);
    float sdx = (float)(u32)(w & 0xFFFFULL)         * (1.0f/16.0f) - 12.0f * cnt;
    float sdy = (float)(u32)((w >> 16) & 0xFFFFULL) * (1.0f/16.0f) - 12.0f * cnt;
    float sux = (float)(u32)((w >> 32) & 0xFFFULL)  * (1.0f/16.0f) -  1.0f * cnt;
    float suy = (float)(u32)((w >> 44) & 0xFFFULL)  * (1.0f/16.0f) -  1.0f * cnt;
    float invc = 1.0f / fmaxf(cnt, 1.0f);
    float2 pp = reinterpret_cast<const float2*>(pos)[i];
    float* row = out + (size_t)i * 6;
    row[0] = sdx * invc;
    row[1] = sdy * invc;
    row[2] = sux * invc;
    row[3] = suy * invc;
    row[4] = pp.x;
    row[5] = pp.y;
}

// ---------------- Fallback (round-3 single-atomic path) ----------------
__global__ void __launch_bounds__(256) edge_scatter_kernel(
    const int* __restrict__ src, const int* __restrict__ dst,
    const float* __restrict__ pos, u64* __restrict__ acc)
{
    int e = blockIdx.x * blockDim.x + threadIdx.x;
    if (e >= N_EDGES) return;
    int s = src[e];
    int d = dst[e];
    if ((unsigned)s >= (unsigned)N_NODES || (unsigned)d >= (unsigned)N_NODES) return;
    float2 ps = reinterpret_cast<const float2*>(pos)[s];
    float2 pd = reinterpret_cast<const float2*>(pos)[d];
    float dx = ps.x - pd.x, dy = ps.y - pd.y;
    float nrm = sqrtf(dx*dx + dy*dy) + EPS;
    float inv = 1.0f / nrm;
    float ux = dx * inv, uy = dy * inv;
    float cdx = fminf(fmaxf(dx, -12.0f), 12.0f);
    float cdy = fminf(fmaxf(dy, -12.0f), 12.0f);
    u64 qdx = (u64)(u32)__float2int_rn((cdx + 12.0f) * 16.0f);
    u64 qdy = (u64)(u32)__float2int_rn((cdy + 12.0f) * 16.0f);
    u64 qux = (u64)(u32)__float2int_rn((ux + 1.0f) * 16.0f);
    u64 quy = (u64)(u32)__float2int_rn((uy + 1.0f) * 16.0f);
    u64 w = qdx | (qdy << 16) | (qux << 32) | (quy << 44) | (1ULL << 56);
    atomicAdd(acc + (size_t)d * 3, w);
}

__global__ void __launch_bounds__(256) node_finalize_kernel(
    const float* __restrict__ pos, float* __restrict__ out)
{
    int i = blockIdx.x * blockDim.x + threadIdx.x;
    if (i >= N_NODES) return;
    u64 w = reinterpret_cast<const u64*>(out)[(size_t)i * 3];
    float cnt = (float)(u32)(w >> 56);
    float sdx = (float)(u32)(w & 0xFFFFULL)         * (1.0f/16.0f) - 12.0f * cnt;
    float sdy = (float)(u32)((w >> 16) & 0xFFFFULL) * (1.0f/16.0f) - 12.0f * cnt;
    float sux = (float)(u32)((w >> 32) & 0xFFFULL)  * (1.0f/16.0f) -  1.0f * cnt;
    float suy = (float)(u32)((w >> 44) & 0xFFFULL)  * (1.0f/16.0f) -  1.0f * cnt;
    float invc = 1.0f / fmaxf(cnt, 1.0f);
    float2 p = reinterpret_cast<const float2*>(pos)[i];
    float* row = out + (size_t)i * 6;
    row[0] = sdx * invc; row[1] = sdy * invc;
    row[2] = sux * invc; row[3] = suy * invc;
    row[4] = p.x; row[5] = p.y;
}

extern "C" void kernel_launch(void* const* d_in, const int* in_sizes, int n_in,
                              void* d_out, int out_size, void* d_ws, size_t ws_size,
                              hipStream_t stream)
{
    const float* pos = (const float*)d_in[0];
    const int* edge_index = (const int*)d_in[1];
    const int* src = edge_index;
    const int* dst = edge_index + N_EDGES;
    float* out = (float*)d_out;

    size_t need_rec  = (size_t)NBLK_A * CHUNK * sizeof(u32);                // ~64 MB
    size_t need_incl = (size_t)NBLK_A * NBINS * sizeof(u32);                // ~4 MB
    size_t need_part = (size_t)NBINS * SPLIT * NODES_PER_BIN * sizeof(u64); // 32 MB
    size_t need = need_rec + need_incl + need_part + 256;

    if (ws_size < need) {
        // Fallback: single-u64-atomic path (round 3)
        (void)hipMemsetAsync(d_out, 0, (size_t)out_size * sizeof(float), stream);
        int eblocks = (N_EDGES + 255) / 256;
        edge_scatter_kernel<<<eblocks, 256, 0, stream>>>(
            src, dst, pos, reinterpret_cast<u64*>(out));
        int nblocks = (N_NODES + 255) / 256;
        node_finalize_kernel<<<nblocks, 256, 0, stream>>>(pos, out);
        return;
    }

    char* w = (char*)d_ws;
    u32* recbuf  = (u32*)w;           w += need_rec;
    u32* inclbuf = (u32*)w;           w += need_incl;
    u64* partial = (u64*)w;

    scatter_kernel<<<NBLK_A, 512, 0, stream>>>(src, dst, recbuf, inclbuf);
    reduce_kernel <<<NBINS * SPLIT, 512, 0, stream>>>(recbuf, inclbuf, pos, partial);
    combine_kernel<<<(N_NODES + 511) / 512, 512, 0, stream>>>(partial, pos, out);
}

// Round 16
// 216.766 us; speedup vs baseline: 1.2070x; 1.1209x over previous
//
#include <hip/hip_runtime.h>
#include <math.h>

#define N_NODES   500000
#define N_EDGES   16000000
#define EPS       1e-6f

#define NBINS         256      // bin = dst >> 11  (2048 nodes per bin)
#define NODES_PER_BIN 2048
#define CHUNK         4096     // edges per scatter block
#define NBLK_A        3907     // ceil(16e6 / 4096)
#define SPLIT         8        // reduce splits per bin
#define BPB           489      // ceil(NBLK_A / SPLIT), <= 512

typedef unsigned long long u64;
typedef unsigned int u32;
typedef unsigned short u16;
typedef u32 v4u __attribute__((ext_vector_type(4)));

// u32 record layout: [0:11) lid = dst & 2047, [11:30) srcid (< 2^19), [30:32) spare.
// Geometry computed at reduce time in exact f32 (round-3 proven math).

// ---- Kernel 1: pure integer counting sort of edges by dst-bin ----
__global__ void __launch_bounds__(512) scatter_kernel(
    const int* __restrict__ src, const int* __restrict__ dst,
    u32* __restrict__ recbuf, u32* __restrict__ inclbuf)
{
    __shared__ u32 stage[CHUNK];       // 16 KB
    __shared__ u16 perm[CHUNK];        // 8 KB
    __shared__ u32 incl[NBINS];        // 1 KB
    __shared__ u32 wsum[4];

    int t = threadIdx.x, b = blockIdx.x;
    int lane = t & 63, wid = t >> 6;
    if (t < NBINS) incl[t] = 0;
    __syncthreads();

    const v4u* src4 = reinterpret_cast<const v4u*>(src);
    const v4u* dst4 = reinterpret_cast<const v4u*>(dst);
    int base4 = b * (CHUNK / 4);

    u32 rb[8];                         // bin(8) << 13 | rank(13); ~0u = invalid
    #pragma unroll
    for (int i = 0; i < 2; ++i) {
        int e4 = base4 + t + i * 512;
        #pragma unroll
        for (int j = 0; j < 4; ++j) rb[i * 4 + j] = 0xFFFFFFFFu;
        if (e4 * 4 < N_EDGES) {
            v4u s4 = __builtin_nontemporal_load(src4 + e4);
            v4u d4 = __builtin_nontemporal_load(dst4 + e4);
            #pragma unroll
            for (int j = 0; j < 4; ++j) {
                u32 s_ = (u32)min(max((int)s4[j], 0), N_NODES - 1);
                u32 d_ = (u32)min(max((int)d4[j], 0), N_NODES - 1);
                u32 rc = (s_ << 11) | (d_ & (NODES_PER_BIN - 1));
                int k = i * 4 + j;
                stage[t + k * 512] = rc;
                u32 bin = d_ >> 11;
                u32 r = atomicAdd(&incl[bin], 1u);
                rb[k] = (bin << 13) | r;
            }
        }
    }
    __syncthreads();

    // in-place inclusive scan of incl[256]
    u32 v = 0;
    if (t < NBINS) {
        v = incl[t];
        #pragma unroll
        for (int off = 1; off < 64; off <<= 1) {
            u32 u_ = __shfl_up(v, off, 64);
            if (lane >= off) v += u_;
        }
        if (lane == 63) wsum[wid] = v;
    }
    __syncthreads();
    if (t < NBINS) {
        u32 pre = 0;
        #pragma unroll
        for (int w2 = 0; w2 < 4; ++w2)
            pre += (w2 < wid) ? wsum[w2] : 0;
        v += pre;
        incl[t] = v;
        __builtin_nontemporal_store(v, inclbuf + (size_t)b * NBINS + t);
    }
    __syncthreads();

    #pragma unroll
    for (int k = 0; k < 8; ++k) {
        if (rb[k] != 0xFFFFFFFFu) {
            u32 bin = rb[k] >> 13;
            u32 r   = rb[k] & 8191u;
            u32 excl = bin ? incl[bin - 1] : 0;
            perm[excl + r] = (u16)(t + k * 512);
        }
    }
    __syncthreads();

    v4u* out4 = reinterpret_cast<v4u*>(recbuf + (size_t)b * CHUNK);
    #pragma unroll
    for (int i = 0; i < 2; ++i) {
        int j4 = t + i * 512;
        v4u o;
        o[0] = stage[perm[j4 * 4 + 0] & (CHUNK - 1)];
        o[1] = stage[perm[j4 * 4 + 1] & (CHUNK - 1)];
        o[2] = stage[perm[j4 * 4 + 2] & (CHUNK - 1)];
        o[3] = stage[perm[j4 * 4 + 3] & (CHUNK - 1)];
        __builtin_nontemporal_store(o, out4 + j4);
    }
}

// ---- Kernel 2: split-K decode + accumulate, flat-indexed for MLP ----
// Directory (489 runs) loaded once into LDS; then a flat loop over the split's
// T records: independent iterations -> multiple gathers in flight per thread.
__global__ void __launch_bounds__(512) reduce_kernel(
    const u32* __restrict__ recbuf, const u32* __restrict__ inclbuf,
    const float* __restrict__ pos, u64* __restrict__ partial)
{
    __shared__ u64 acc[NODES_PER_BIN];   // 16 KB
    __shared__ u32 pref[512];            // inclusive prefix of run lengths
    __shared__ u32 rstart[512];          // global record index of each run start
    __shared__ u32 wsum[8];

    int t = threadIdx.x;
    int k = blockIdx.x / SPLIT;
    int s = blockIdx.x % SPLIT;
    int lane = t & 63, wid = t >> 6;
    #pragma unroll
    for (int i = 0; i < 4; ++i) acc[t + i * 512] = 0;

    // one-time directory load: run (length, start) for source blocks of split s
    int b = s * BPB + t;
    u32 len = 0, st = 0;
    if (t < BPB && b < NBLK_A) {
        const u32* ib = inclbuf + (size_t)b * NBINS;
        u32 hi = ib[k];
        u32 lo = k ? ib[k - 1] : 0;
        len = hi - lo;
        st = (u32)b * CHUNK + lo;
    }
    rstart[t] = st;

    // block-wide inclusive scan of len -> pref
    u32 v = len;
    #pragma unroll
    for (int off = 1; off < 64; off <<= 1) {
        u32 u_ = __shfl_up(v, off, 64);
        if (lane >= off) v += u_;
    }
    if (lane == 63) wsum[wid] = v;
    __syncthreads();
    u32 pre = 0;
    #pragma unroll
    for (int w2 = 0; w2 < 8; ++w2)
        pre += (w2 < wid) ? wsum[w2] : 0;
    v += pre;
    pref[t] = v;
    __syncthreads();
    u32 T = pref[511];

    const float2* pos2 = reinterpret_cast<const float2*>(pos);
    int nodebase = k * NODES_PER_BIN;

    #pragma unroll 2
    for (u32 idx = t; idx < T; idx += 512) {
        // smallest r with pref[r] > idx (9-step LDS binary search)
        u32 lo_ = 0, hi_ = 511;
        #pragma unroll
        for (int it = 0; it < 9; ++it) {
            u32 mid = (lo_ + hi_) >> 1;
            if (idx < pref[mid]) hi_ = mid; else lo_ = mid + 1;
        }
        u32 r = lo_;
        u32 base = r ? pref[r - 1] : 0;
        u32 rc = recbuf[rstart[r] + (idx - base)];
        u32 lid  = rc & (NODES_PER_BIN - 1);
        u32 sidx = rc >> 11;
        float2 ps = pos2[sidx];              // the one random gather
        float2 pd = pos2[nodebase + lid];    // L1-hot 16 KB window
        float dx = ps.x - pd.x;
        float dy = ps.y - pd.y;
        float nrm = sqrtf(dx * dx + dy * dy) + EPS;
        float inv = 1.0f / nrm;
        float ux = dx * inv, uy = dy * inv;
        float cdx = fminf(fmaxf(dx, -12.0f), 12.0f);
        float cdy = fminf(fmaxf(dy, -12.0f), 12.0f);
        u32 qdx = (u32)__float2int_rn((cdx + 12.0f) * 16.0f);
        u32 qdy = (u32)__float2int_rn((cdy + 12.0f) * 16.0f);
        u32 qux = (u32)__float2int_rn((ux + 1.0f) * 16.0f);
        u32 quy = (u32)__float2int_rn((uy + 1.0f) * 16.0f);
        u64 w = (u64)qdx | ((u64)qdy << 16) | ((u64)qux << 32)
              | ((u64)quy << 44) | (1ULL << 56);
        atomicAdd(&acc[lid], w);
    }
    __syncthreads();

    u64* dstp = partial + ((size_t)k * SPLIT + s) * NODES_PER_BIN;
    #pragma unroll
    for (int i = 0; i < 4; ++i) {
        int idx = t + i * 512;
        __builtin_nontemporal_store(acc[idx], dstp + idx);
    }
}

// ---- Kernel 3: combine partials + finalize ----
__global__ void __launch_bounds__(512) combine_kernel(
    const u64* __restrict__ partial, const float* __restrict__ pos,
    float* __restrict__ out)
{
    int i = blockIdx.x * 512 + threadIdx.x;
    if (i >= N_NODES) return;
    int k = i >> 11;
    int lid = i & (NODES_PER_BIN - 1);
    const u64* p = partial + (size_t)k * SPLIT * NODES_PER_BIN + lid;
    u64 w = 0;
    #pragma unroll
    for (int s = 0; s < SPLIT; ++s)
        w += __builtin_nontemporal_load(p + (size_t)s * NODES_PER_BIN);

    float cnt = (float)(u32)(w >> 56);
    float sdx = (float)(u32)(w & 0xFFFFULL)         * (1.0f/16.0f) - 12.0f * cnt;
    float sdy = (float)(u32)((w >> 16) & 0xFFFFULL) * (1.0f/16.0f) - 12.0f * cnt;
    float sux = (float)(u32)((w >> 32) & 0xFFFULL)  * (1.0f/16.0f) -  1.0f * cnt;
    float suy = (float)(u32)((w >> 44) & 0xFFFULL)  * (1.0f/16.0f) -  1.0f * cnt;
    float invc = 1.0f / fmaxf(cnt, 1.0f);
    float2 pp = reinterpret_cast<const float2*>(pos)[i];
    float* row = out + (size_t)i * 6;
    row[0] = sdx * invc;
    row[1] = sdy * invc;
    row[2] = sux * invc;
    row[3] = suy * invc;
    row[4] = pp.x;
    row[5] = pp.y;
}

// ---------------- Fallback (round-3 single-atomic path) ----------------
__global__ void __launch_bounds__(256) edge_scatter_kernel(
    const int* __restrict__ src, const int* __restrict__ dst,
    const float* __restrict__ pos, u64* __restrict__ acc)
{
    int e = blockIdx.x * blockDim.x + threadIdx.x;
    if (e >= N_EDGES) return;
    int s = src[e];
    int d = dst[e];
    if ((unsigned)s >= (unsigned)N_NODES || (unsigned)d >= (unsigned)N_NODES) return;
    float2 ps = reinterpret_cast<const float2*>(pos)[s];
    float2 pd = reinterpret_cast<const float2*>(pos)[d];
    float dx = ps.x - pd.x, dy = ps.y - pd.y;
    float nrm = sqrtf(dx*dx + dy*dy) + EPS;
    float inv = 1.0f / nrm;
    float ux = dx * inv, uy = dy * inv;
    float cdx = fminf(fmaxf(dx, -12.0f), 12.0f);
    float cdy = fminf(fmaxf(dy, -12.0f), 12.0f);
    u64 qdx = (u64)(u32)__float2int_rn((cdx + 12.0f) * 16.0f);
    u64 qdy = (u64)(u32)__float2int_rn((cdy + 12.0f) * 16.0f);
    u64 qux = (u64)(u32)__float2int_rn((ux + 1.0f) * 16.0f);
    u64 quy = (u64)(u32)__float2int_rn((uy + 1.0f) * 16.0f);
    u64 w = qdx | (qdy << 16) | (qux << 32) | (quy << 44) | (1ULL << 56);
    atomicAdd(acc + (size_t)d * 3, w);
}

__global__ void __launch_bounds__(256) node_finalize_kernel(
    const float* __restrict__ pos, float* __restrict__ out)
{
    int i = blockIdx.x * blockDim.x + threadIdx.x;
    if (i >= N_NODES) return;
    u64 w = reinterpret_cast<const u64*>(out)[(size_t)i * 3];
    float cnt = (float)(u32)(w >> 56);
    float sdx = (float)(u32)(w & 0xFFFFULL)         * (1.0f/16.0f) - 12.0f * cnt;
    float sdy = (float)(u32)((w >> 16) & 0xFFFFULL) * (1.0f/16.0f) - 12.0f * cnt;
    float sux = (float)(u32)((w >> 32) & 0xFFFULL)  * (1.0f/16.0f) -  1.0f * cnt;
    float suy = (float)(u32)((w >> 44) & 0xFFFULL)  * (1.0f/16.0f) -  1.0f * cnt;
    float invc = 1.0f / fmaxf(cnt, 1.0f);
    float2 p = reinterpret_cast<const float2*>(pos)[i];
    float* row = out + (size_t)i * 6;
    row[0] = sdx * invc; row[1] = sdy * invc;
    row[2] = sux * invc; row[3] = suy * invc;
    row[4] = p.x; row[5] = p.y;
}

extern "C" void kernel_launch(void* const* d_in, const int* in_sizes, int n_in,
                              void* d_out, int out_size, void* d_ws, size_t ws_size,
                              hipStream_t stream)
{
    const float* pos = (const float*)d_in[0];
    const int* edge_index = (const int*)d_in[1];
    const int* src = edge_index;
    const int* dst = edge_index + N_EDGES;
    float* out = (float*)d_out;

    size_t need_rec  = (size_t)NBLK_A * CHUNK * sizeof(u32);                // ~64 MB
    size_t need_incl = (size_t)NBLK_A * NBINS * sizeof(u32);                // ~4 MB
    size_t need_part = (size_t)NBINS * SPLIT * NODES_PER_BIN * sizeof(u64); // 32 MB
    size_t need = need_rec + need_incl + need_part + 256;

    if (ws_size < need) {
        // Fallback: single-u64-atomic path (round 3)
        (void)hipMemsetAsync(d_out, 0, (size_t)out_size * sizeof(float), stream);
        int eblocks = (N_EDGES + 255) / 256;
        edge_scatter_kernel<<<eblocks, 256, 0, stream>>>(
            src, dst, pos, reinterpret_cast<u64*>(out));
        int nblocks = (N_NODES + 255) / 256;
        node_finalize_kernel<<<nblocks, 256, 0, stream>>>(pos, out);
        return;
    }

    char* w = (char*)d_ws;
    u32* recbuf  = (u32*)w;           w += need_rec;
    u32* inclbuf = (u32*)w;           w += need_incl;
    u64* partial = (u64*)w;

    scatter_kernel<<<NBLK_A, 512, 0, stream>>>(src, dst, recbuf, inclbuf);
    reduce_kernel <<<NBINS * SPLIT, 512, 0, stream>>>(recbuf, inclbuf, pos, partial);
    combine_kernel<<<(N_NODES + 511) / 512, 512, 0, stream>>>(partial, pos, out);
}